// Round 8
// baseline (38.870 us; speedup 1.0000x reference)
//
#include <hip/hip_runtime.h>
#include <math.h>

// Problem constants (fixed by reference setup_inputs)
#define P_    256           // identities
#define K_    16            // instances per group
#define C4_   1024          // float4 per row (C=4096)
#define N_    8192          // 2*P*K rows
#define TWOP  512           // groups
#define NSL   16            // column slices (each 64 float4 = 256 floats)
#define NTAILB 32           // k_tail blocks (one thread per row)
#define MARGIN_F 0.6f
#define EXCAP   8192
#define FLAGCAP 16384

__device__ __forceinline__ float wave_reduce_f(float v) {
    #pragma unroll
    for (int o = 32; o > 0; o >>= 1) v += __shfl_xor(v, o, 64);
    return v;
}

// 16-value multi-butterfly: after call, every lane's val[0] holds the 64-lane
// total of value index bitrev4(lane&15). 17 shuffles. (Verified rounds 4-7.)
__device__ __forceinline__ void bfly16(float val[16], const int lane) {
    #define BFLY_STAGE(MASK, HALF)                                          \
    {                                                                       \
        const bool upper = (lane & MASK) != 0;                              \
        _Pragma("unroll")                                                   \
        for (int i = 0; i < HALF; ++i) {                                    \
            const float send = upper ? val[i] : val[i + HALF];              \
            const float recv = __shfl_xor(send, MASK, 64);                  \
            val[i] = (upper ? val[i + HALF] : val[i]) + recv;               \
        }                                                                   \
    }
    BFLY_STAGE(1, 8)
    BFLY_STAGE(2, 4)
    BFLY_STAGE(4, 2)
    BFLY_STAGE(8, 1)
    #undef BFLY_STAGE
    val[0] += __shfl_xor(val[0], 16, 64);
    val[0] += __shfl_xor(val[0], 32, 64);
}

__device__ __forceinline__ int bitrev4(const int m) {
    return ((m & 1) << 3) | ((m & 2) << 1) | ((m & 4) >> 1) | ((m & 8) >> 3);
}

// LDS-only barrier: waits ds ops, does NOT drain vmcnt (keeps the second
// slice's global loads in flight across the barrier).
__device__ __forceinline__ void barrier_lds_only() {
    asm volatile("s_waitcnt lgkmcnt(0)\n\ts_barrier" ::: "memory");
}

// counters: [0]=extracnt [1]=flagcnt [2]=ovf [3]=tail-arrival
// ---------------------------------------------------------------------------
// k_fused: one block per (pair p, slice-pair sp); 128 threads = 2 waves
// (wave = side A/B). Each thread holds 16 rows x 1 column for TWO slices
// (sp and sp+8) in registers. Slice-B loads are issued up front and stay in
// flight across slice-A's barrier (raw s_barrier, lgkmcnt-only wait), so the
// post-barrier dot/butterfly phase overlaps slice-B's memory traffic.
__global__ __launch_bounds__(128) void k_fused(const float* __restrict__ x,
                                               float* __restrict__ dot_part,
                                               float* __restrict__ sq_part,
                                               float* __restrict__ hn2_part,
                                               unsigned* __restrict__ counters) {
    const int blk = blockIdx.x;      // 0..2047
    const int p = blk >> 3;          // pair 0..255
    const int sp = blk & 7;          // slice-pair 0..7: slices sp and sp+8
    const int t = threadIdx.x;       // 0..127
    const int lane = t & 63;
    const int side = t >> 6;         // wave 0 = A (grp p), wave 1 = B (grp P_+p)

    if (blk == 0 && t < 4) counters[t] = 0u;

    __shared__ float4 cen[2][2][64];   // [buf][side][lane] 4 KB

    const float4* x4 = (const float4*)x;
    const int grp = side ? (P_ + p) : p;
    const size_t rowbase = (size_t)grp * K_ * C4_;
    const int colA = sp * 64 + lane;
    const int colB = (sp + 8) * 64 + lane;

    // issue ALL 32 loads up front (A then B); B stays in flight during A's
    // compute + barrier.
    float4 vA[16], vB[16];
    #pragma unroll
    for (int r = 0; r < 16; ++r) vA[r] = x4[rowbase + (size_t)r * C4_ + colA];
    #pragma unroll
    for (int r = 0; r < 16; ++r) vB[r] = x4[rowbase + (size_t)r * C4_ + colB];

    // ---------------- slice A ----------------
    float4 csA = {0.f, 0.f, 0.f, 0.f};
    float sqA[16];
    #pragma unroll
    for (int r = 0; r < 16; ++r) {
        csA.x += vA[r].x; csA.y += vA[r].y; csA.z += vA[r].z; csA.w += vA[r].w;
        sqA[r] = vA[r].x*vA[r].x + vA[r].y*vA[r].y + vA[r].z*vA[r].z + vA[r].w*vA[r].w;
    }
    bfly16(sqA, lane);                       // pre-barrier: shrink post-barrier phase
    const int obA = ((p * NSL + sp) * 2 + side) * 16;
    if (lane < 16) sq_part[obA + bitrev4(lane)] = sqA[0];

    cen[0][side][lane] = csA;
    float h2A = csA.x*csA.x + csA.y*csA.y + csA.z*csA.z + csA.w*csA.w;
    h2A = wave_reduce_f(h2A);
    if (lane == 0) hn2_part[(p * NSL + sp) * 2 + side] = h2A;   // raw |S|^2 partial

    barrier_lds_only();                      // vB loads remain outstanding

    const float4 hpA = cen[0][side ^ 1][lane];
    float dpA[16];
    #pragma unroll
    for (int r = 0; r < 16; ++r)
        dpA[r] = vA[r].x*hpA.x + vA[r].y*hpA.y + vA[r].z*hpA.z + vA[r].w*hpA.w;
    bfly16(dpA, lane);
    if (lane < 16) dot_part[obA + bitrev4(lane)] = dpA[0];

    // ---------------- slice B ----------------
    float4 csB = {0.f, 0.f, 0.f, 0.f};
    float sqB[16];
    #pragma unroll
    for (int r = 0; r < 16; ++r) {
        csB.x += vB[r].x; csB.y += vB[r].y; csB.z += vB[r].z; csB.w += vB[r].w;
        sqB[r] = vB[r].x*vB[r].x + vB[r].y*vB[r].y + vB[r].z*vB[r].z + vB[r].w*vB[r].w;
    }
    bfly16(sqB, lane);
    const int sB = sp + 8;
    const int obB = ((p * NSL + sB) * 2 + side) * 16;
    if (lane < 16) sq_part[obB + bitrev4(lane)] = sqB[0];

    cen[1][side][lane] = csB;
    float h2B = csB.x*csB.x + csB.y*csB.y + csB.z*csB.z + csB.w*csB.w;
    h2B = wave_reduce_f(h2B);
    if (lane == 0) hn2_part[(p * NSL + sB) * 2 + side] = h2B;

    barrier_lds_only();

    const float4 hpB = cen[1][side ^ 1][lane];
    float dpB[16];
    #pragma unroll
    for (int r = 0; r < 16; ++r)
        dpB[r] = vB[r].x*hpB.x + vB[r].y*hpB.y + vB[r].z*hpB.z + vB[r].w*hpB.w;
    bfly16(dpB, lane);
    if (lane < 16) dot_part[obB + bitrev4(lane)] = dpB[0];
}

// ---------------------------------------------------------------------------
// k_tail: one thread per row; slice-combine -> dist; structured fast path or
// exact per-row scan (general pids). Last-arriving block performs the final
// reduction + exact fallback + scalar emit. (Structure proven rounds 5-7.)
__global__ __launch_bounds__(256) void k_tail(const float* __restrict__ x,
                                              const float* __restrict__ dot_part,
                                              const float* __restrict__ sq_part,
                                              const float* __restrict__ hn2_part,
                                              const int* __restrict__ pids,
                                              float* __restrict__ s1part,
                                              unsigned* __restrict__ c1part,
                                              unsigned* __restrict__ negpart,
                                              unsigned* __restrict__ counters,
                                              int* __restrict__ extralist,
                                              int* __restrict__ flaglist,
                                              float* __restrict__ out) {
    __shared__ int   gp[TWOP];
    __shared__ float shn[TWOP], sh2[TWOP];
    __shared__ int   s_ok, sLast;
    __shared__ float smin[4], smax[4];
    __shared__ float rf[4];
    __shared__ unsigned ru[4], rn[4];
    __shared__ float bc_s1, bc_c1, bc_ng;
    const int t = threadIdx.x;
    const int lane = t & 63, wv = t >> 6;

    if (t == 0) s_ok = 1;
    __syncthreads();

    float lmin = 3.0e38f, lmax = -3.0e38f;
    for (int j = t; j < TWOP; j += 256) {
        const int g = pids[j * K_];
        gp[j] = g;
        if (g != (j & (P_ - 1))) s_ok = 0;   // structured-layout check
        const int side = (j < P_) ? 0 : 1;
        const int pp = j & (P_ - 1);
        float a = 0.f;
        #pragma unroll
        for (int ss = 0; ss < NSL; ++ss)
            a += hn2_part[(pp * NSL + ss) * 2 + side];
        a *= (1.0f / 256.0f);                // |h|^2 = |S|^2 / K^2
        sh2[j] = a;
        const float r = sqrtf(a);
        shn[j] = r;
        lmin = fminf(lmin, r); lmax = fmaxf(lmax, r);
    }
    #pragma unroll
    for (int o = 32; o > 0; o >>= 1) {
        lmin = fminf(lmin, __shfl_xor(lmin, o, 64));
        lmax = fmaxf(lmax, __shfl_xor(lmax, o, 64));
    }
    if (lane == 0) { smin[wv] = lmin; smax[wv] = lmax; }
    __syncthreads();
    const float hmin = fminf(fminf(smin[0], smin[1]), fminf(smin[2], smin[3]));
    const float hmax = fmaxf(fmaxf(smax[0], smax[1]), fmaxf(smax[2], smax[3]));
    const int structured = s_ok;

    const int gr  = blockIdx.x * 256 + t;     // row 0..8191
    const int grp = gr >> 4, kk = gr & 15;
    const int pp2 = grp & (P_ - 1);
    const int sideR = (grp < P_) ? 0 : 1;
    const int pg  = (grp < P_) ? (P_ + pp2) : pp2;  // structural partner group

    float dot = 0.f, sq = 0.f;
    #pragma unroll
    for (int ss = 0; ss < NSL; ++ss) {
        const int sb = ((pp2 * NSL + ss) * 2 + sideR) * 16 + kk;
        dot += dot_part[sb];
        sq  += sq_part [sb];
    }
    // dist^2 = |x|^2 + |h|^2 - 2 x.h;  x.h = dot_raw/16
    const float dist = sqrtf(fmaxf(sq + sh2[pg] - 0.125f * dot, 1e-12f));
    const float myxn = sqrtf(sq);
    const int mypid = pids[gr];
    const bool window_clear = (myxn >= hmax + MARGIN_F) || (myxn <= hmin - MARGIN_F);

    unsigned mall, mopp;
    if (structured && mypid == pp2 && window_clear) {
        mall = 2u; mopp = 1u;    // canonical: matches are exactly {p, P_+p}
    } else {
        const int jb = (gr < N_ / 2) ? P_ : 0;
        mall = 0u; mopp = 0u;
        for (int j = 0; j < TWOP; ++j) {
            if (gp[j] == mypid) {
                ++mall;
                if (j >= jb && j < jb + P_) {
                    ++mopp;
                    if (j != pg) {
                        unsigned s0 = atomicAdd(&counters[0], 1u);
                        if (s0 < EXCAP) extralist[s0] = gr * TWOP + j;
                        else atomicExch(&counters[2], 1u);
                    }
                }
            } else if (fabsf(myxn - shn[j]) < MARGIN_F) {
                unsigned s0 = atomicAdd(&counters[1], 1u);
                if (s0 < FLAGCAP) flaglist[s0] = gr * TWOP + j;
                else atomicExch(&counters[2], 1u);
            }
        }
    }

    float s1 = (gp[pg] == mypid) ? dist : 0.f;
    unsigned neg = (unsigned)TWOP - mall;
    unsigned mo = mopp;
    #pragma unroll
    for (int o = 32; o > 0; o >>= 1) {
        s1  += __shfl_xor(s1, o, 64);
        mo  += __shfl_xor(mo, o, 64);
        neg += __shfl_xor(neg, o, 64);
    }
    if (lane == 0) { rf[wv] = s1; ru[wv] = mo; rn[wv] = neg; }
    __syncthreads();
    if (t == 0) {
        atomicExch(&s1part[blockIdx.x],  rf[0] + rf[1] + rf[2] + rf[3]);
        atomicExch(&c1part[blockIdx.x],  ru[0] + ru[1] + ru[2] + ru[3]);
        atomicExch(&negpart[blockIdx.x], rn[0] + rn[1] + rn[2] + rn[3]);
    }

    // ---- arrival: last block performs final phase
    __threadfence();
    if (t == 0) {
        const unsigned n = atomicAdd(&counters[3], 1u);
        sLast = (n == NTAILB - 1) ? 1 : 0;
    }
    __syncthreads();
    if (!sLast) return;
    __threadfence();   // acquire: see all blocks' partials/lists

    {
        float s1v = 0.f; unsigned c1v = 0u, ngv = 0u;
        if (t < NTAILB) { s1v = s1part[t]; c1v = c1part[t]; ngv = negpart[t]; }
        if (t < 64) {
            #pragma unroll
            for (int o = 32; o > 0; o >>= 1) {
                s1v += __shfl_xor(s1v, o, 64);
                c1v += __shfl_xor(c1v, o, 64);
                ngv += __shfl_xor(ngv, o, 64);
            }
            if (t == 0) { bc_s1 = s1v; bc_c1 = (float)c1v; bc_ng = (float)ngv; }
        }
    }
    __syncthreads();

    // exact fallback for extras (loss1) and flagged pairs (hinge); expected 0
    unsigned ne = counters[0]; if (ne > EXCAP)   ne = EXCAP;
    unsigned nf = counters[1]; if (nf > FLAGCAP) nf = FLAGCAP;
    float s1x = 0.f, l2 = 0.f;
    const float4* x4 = (const float4*)x;
    for (unsigned u = 0; u < ne + nf; ++u) {
        const bool isex = (u < ne);
        const int code = isex ? extralist[u] : flaglist[u - ne];
        const int i = code >> 9, jj = code & (TWOP - 1);
        const float4* xr = x4 + (size_t)i * C4_;
        const float4* gb = x4 + (size_t)jj * K_ * C4_;
        float dpv = 0.f, sqi = 0.f;
        for (int c = t; c < C4_; c += 256) {
            const float4 a = xr[c];
            float hx = 0.f, hy = 0.f, hz = 0.f, hw = 0.f;
            #pragma unroll
            for (int rr = 0; rr < K_; ++rr) {
                const float4 u4 = gb[(size_t)rr * C4_ + c];
                hx += u4.x; hy += u4.y; hz += u4.z; hw += u4.w;
            }
            dpv += (a.x*hx + a.y*hy + a.z*hz + a.w*hw) * 0.0625f;
            sqi += a.x*a.x + a.y*a.y + a.z*a.z + a.w*a.w;
        }
        #pragma unroll
        for (int o = 32; o > 0; o >>= 1) {
            dpv += __shfl_xor(dpv, o, 64);
            sqi += __shfl_xor(sqi, o, 64);
        }
        if (lane == 0) { rf[wv] = dpv; smin[wv] = sqi; }
        __syncthreads();
        if (t == 0) {
            const float ddot = rf[0] + rf[1] + rf[2] + rf[3];
            const float sqv  = smin[0] + smin[1] + smin[2] + smin[3];
            const float d2 = sqv + sh2[jj] - 2.0f * ddot;
            const float dist2 = sqrtf(fmaxf(d2, 1e-12f));
            if (isex) s1x += dist2;
            else { const float h = MARGIN_F - dist2; if (h > 0.f) l2 += h; }
        }
        __syncthreads();
    }

    if (t == 0) out[0] = (bc_s1 + s1x) / bc_c1 + l2 / bc_ng;
}

// ---------------------------------------------------------------------------
extern "C" void kernel_launch(void* const* d_in, const int* in_sizes, int n_in,
                              void* d_out, int out_size, void* d_ws, size_t ws_size,
                              hipStream_t stream) {
    const float* x    = (const float*)d_in[0];
    const int*   pids = (const int*)d_in[1];

    float* ws = (float*)d_ws;
    float*    dot_part = ws;                                    // 256*16*32 = 131072
    float*    sq_part  = dot_part + P_ * NSL * 32;              // 131072
    float*    hn2_part = sq_part + P_ * NSL * 32;               // 256*16*2 = 8192
    float*    s1part   = hn2_part + P_ * NSL * 2;               // 32
    unsigned* c1part   = (unsigned*)(s1part + NTAILB);          // 32
    unsigned* negpart  = c1part + NTAILB;                       // 32
    unsigned* counters = negpart + NTAILB;                      // 4
    int*      extralist= (int*)(counters + 4);                  // EXCAP
    int*      flaglist = extralist + EXCAP;                     // FLAGCAP

    hipLaunchKernelGGL(k_fused, dim3(P_ * 8), dim3(128), 0, stream,
                       x, dot_part, sq_part, hn2_part, counters);
    hipLaunchKernelGGL(k_tail,  dim3(NTAILB), dim3(256), 0, stream,
                       x, dot_part, sq_part, hn2_part, pids,
                       s1part, c1part, negpart, counters,
                       extralist, flaglist, (float*)d_out);
}

// Round 9
// 35.043 us; speedup vs baseline: 1.1092x; 1.1092x over previous
//
#include <hip/hip_runtime.h>
#include <math.h>

// Problem constants (fixed by reference setup_inputs)
#define P_    256           // identities
#define K_    16            // instances per group
#define C4_   1024          // float4 per row (C=4096)
#define N_    8192          // 2*P*K rows
#define TWOP  512           // groups
#define NSL   8             // column slices (each 128 float4 = 512 floats)
#define NTAILB 32           // k_tail blocks (32*256 = one thread per row)
#define MARGIN_F 0.6f
#define EXCAP   8192
#define FLAGCAP 16384

__device__ __forceinline__ float wave_reduce_f(float v) {
    #pragma unroll
    for (int o = 32; o > 0; o >>= 1) v += __shfl_xor(v, o, 64);
    return v;
}

// ---------------------------------------------------------------------------
// k_fused: one block per (pair p, slice s); slice = 128 float4 (two 64-lane
// chunks). Wave wv holds 8 row-slices (4 A-rows + 4 B-rows) x 2 chunks in
// registers (16 float4). Centers via LDS partial combine (all 4 waves busy:
// A0/A1/B0/B1). 16 per-wave scalars reduced with one multi-value butterfly.
// x read exactly once. Block 0 zeroes the 4 global counters.
__global__ __launch_bounds__(256) void k_fused(const float* __restrict__ x,
                                               float* __restrict__ dot_part,
                                               float* __restrict__ sq_part,
                                               float* __restrict__ hn2_part,
                                               unsigned* __restrict__ counters) {
    const int blk = blockIdx.x;
    const int p = blk >> 3;          // pair 0..255
    const int s = blk & (NSL - 1);   // slice 0..7
    const int t = threadIdx.x;
    const int lane = t & 63;
    const int wv = t >> 6;           // wave 0..3

    if (blk == 0 && t < 4) counters[t] = 0u;  // extracnt, flagcnt, ovf, done

    __shared__ float4 part[4][4][64];  // [wave][task A0,A1,B0,B1][lane] 16 KB
    __shared__ float4 sh[4][64];       // [task][lane] center chunks    4 KB

    const float4* x4 = (const float4*)x;
    const int col0 = s * 128 + lane;

    // wave wv owns rows r = q*4 + wv: q<4 -> A-rows (grp p), q>=4 -> B-rows
    float4 v0[8], v1[8];
    #pragma unroll
    for (int q = 0; q < 8; ++q) {
        const int r = q * 4 + wv;
        const int grp = (r < 16) ? p : (P_ + p);
        const size_t base = ((size_t)grp * K_ + (r & 15)) * C4_ + col0;
        v0[q] = x4[base];
        v1[q] = x4[base + 64];
    }
    float4 sA0 = {0,0,0,0}, sA1 = sA0, sB0 = sA0, sB1 = sA0;
    #pragma unroll
    for (int q = 0; q < 4; ++q) {
        sA0.x += v0[q].x; sA0.y += v0[q].y; sA0.z += v0[q].z; sA0.w += v0[q].w;
        sA1.x += v1[q].x; sA1.y += v1[q].y; sA1.z += v1[q].z; sA1.w += v1[q].w;
    }
    #pragma unroll
    for (int q = 4; q < 8; ++q) {
        sB0.x += v0[q].x; sB0.y += v0[q].y; sB0.z += v0[q].z; sB0.w += v0[q].w;
        sB1.x += v1[q].x; sB1.y += v1[q].y; sB1.z += v1[q].z; sB1.w += v1[q].w;
    }
    part[wv][0][lane] = sA0;
    part[wv][1][lane] = sA1;
    part[wv][2][lane] = sB0;
    part[wv][3][lane] = sB1;
    __syncthreads();

    // combine: wave wv handles task wv (A.c0, A.c1, B.c0, B.c1)
    {
        const float4 u0 = part[0][wv][lane], u1 = part[1][wv][lane];
        const float4 u2 = part[2][wv][lane], u3 = part[3][wv][lane];
        float4 a;
        a.x = (u0.x+u1.x+u2.x+u3.x) * 0.0625f;
        a.y = (u0.y+u1.y+u2.y+u3.y) * 0.0625f;
        a.z = (u0.z+u1.z+u2.z+u3.z) * 0.0625f;
        a.w = (u0.w+u1.w+u2.w+u3.w) * 0.0625f;
        sh[wv][lane] = a;
        float hn = a.x*a.x + a.y*a.y + a.z*a.z + a.w*a.w;
        hn = wave_reduce_f(hn);
        if (lane == 0) hn2_part[(p * NSL + s) * 4 + wv] = hn;
    }
    __syncthreads();

    const float4 hA0 = sh[0][lane], hA1 = sh[1][lane];
    const float4 hB0 = sh[2][lane], hB1 = sh[3][lane];

    // val[0..7] = dot(row q, partner center), val[8..15] = |row q|^2
    float val[16];
    #pragma unroll
    for (int q = 0; q < 8; ++q) {
        const float4 a0 = v0[q], a1 = v1[q];
        const float4 h0 = (q < 4) ? hB0 : hA0;
        const float4 h1 = (q < 4) ? hB1 : hA1;
        val[q]     = a0.x*h0.x + a0.y*h0.y + a0.z*h0.z + a0.w*h0.w
                   + a1.x*h1.x + a1.y*h1.y + a1.z*h1.z + a1.w*h1.w;
        val[8 + q] = a0.x*a0.x + a0.y*a0.y + a0.z*a0.z + a0.w*a0.w
                   + a1.x*a1.x + a1.y*a1.y + a1.z*a1.z + a1.w*a1.w;
    }

    // multi-value butterfly: 16 independent 64-lane reductions in 17 shfl.
    #define BFLY_STAGE(MASK, HALF)                                          \
    {                                                                       \
        const bool upper = (lane & MASK) != 0;                              \
        _Pragma("unroll")                                                   \
        for (int i = 0; i < HALF; ++i) {                                    \
            const float send = upper ? val[i] : val[i + HALF];              \
            const float recv = __shfl_xor(send, MASK, 64);                  \
            val[i] = (upper ? val[i + HALF] : val[i]) + recv;               \
        }                                                                   \
    }
    BFLY_STAGE(1, 8)
    BFLY_STAGE(2, 4)
    BFLY_STAGE(4, 2)
    BFLY_STAGE(8, 1)
    #undef BFLY_STAGE
    val[0] += __shfl_xor(val[0], 16, 64);
    val[0] += __shfl_xor(val[0], 32, 64);

    // lane m (m<16) holds the total for value index bitreverse4(m)
    if (lane < 16) {
        const int idx = ((lane & 1) << 3) | ((lane & 2) << 1)
                      | ((lane & 4) >> 1) | ((lane & 8) >> 3);
        const int outbase = (p * NSL + s) * 32;
        if (idx < 8) dot_part[outbase + idx * 4 + wv] = val[0];
        else         sq_part [outbase + (idx - 8) * 4 + wv] = val[0];
    }
}

// ---------------------------------------------------------------------------
// k_tail: one thread per row; slice-combine -> dist; structured fast path or
// exact per-row scan (general pids). Last-arriving block performs the final
// reduction + exact fallback + scalar emit (fence/arrival pattern).
__global__ __launch_bounds__(256) void k_tail(const float* __restrict__ x,
                                              const float* __restrict__ dot_part,
                                              const float* __restrict__ sq_part,
                                              const float* __restrict__ hn2_part,
                                              const int* __restrict__ pids,
                                              float* __restrict__ s1part,
                                              unsigned* __restrict__ c1part,
                                              unsigned* __restrict__ negpart,
                                              unsigned* __restrict__ counters,
                                              int* __restrict__ extralist,
                                              int* __restrict__ flaglist,
                                              float* __restrict__ out) {
    __shared__ int   gp[TWOP];
    __shared__ float shn[TWOP], sh2[TWOP];
    __shared__ int   s_ok, sLast;
    __shared__ float smin[4], smax[4];
    __shared__ float rf[4];
    __shared__ unsigned ru[4], rn[4];
    __shared__ float bc_s1, bc_c1, bc_ng;
    const int t = threadIdx.x;
    const int lane = t & 63, wv = t >> 6;

    if (t == 0) s_ok = 1;
    __syncthreads();

    float lmin = 3.0e38f, lmax = -3.0e38f;
    for (int j = t; j < TWOP; j += 256) {
        const int g = pids[j * K_];
        gp[j] = g;
        if (g != (j & (P_ - 1))) s_ok = 0;   // structured-layout check
        const int side = (j < P_) ? 0 : 1;
        const int pp = j & (P_ - 1);
        float a = 0.f;
        #pragma unroll
        for (int ss = 0; ss < NSL; ++ss) {
            a += hn2_part[(pp * NSL + ss) * 4 + side * 2];
            a += hn2_part[(pp * NSL + ss) * 4 + side * 2 + 1];
        }
        sh2[j] = a;
        const float r = sqrtf(a);
        shn[j] = r;
        lmin = fminf(lmin, r); lmax = fmaxf(lmax, r);
    }
    #pragma unroll
    for (int o = 32; o > 0; o >>= 1) {
        lmin = fminf(lmin, __shfl_xor(lmin, o, 64));
        lmax = fmaxf(lmax, __shfl_xor(lmax, o, 64));
    }
    if (lane == 0) { smin[wv] = lmin; smax[wv] = lmax; }
    __syncthreads();
    const float hmin = fminf(fminf(smin[0], smin[1]), fminf(smin[2], smin[3]));
    const float hmax = fmaxf(fmaxf(smax[0], smax[1]), fmaxf(smax[2], smax[3]));
    const int structured = s_ok;

    const int gr  = blockIdx.x * 256 + t;     // row 0..8191
    const int grp = gr >> 4, kk = gr & 15;
    const int pp2 = grp & (P_ - 1);
    const int r   = (grp < P_) ? kk : 16 + kk;
    const int pg  = (grp < P_) ? (P_ + pp2) : pp2;  // structural partner group

    float dot = 0.f, sq = 0.f;
    #pragma unroll
    for (int ss = 0; ss < NSL; ++ss) {
        dot += dot_part[(pp2 * NSL + ss) * 32 + r];
        sq  += sq_part [(pp2 * NSL + ss) * 32 + r];
    }
    const float dist = sqrtf(fmaxf(sq + sh2[pg] - 2.0f * dot, 1e-12f));
    const float myxn = sqrtf(sq);
    const int mypid = pids[gr];
    const bool window_clear = (myxn >= hmax + MARGIN_F) || (myxn <= hmin - MARGIN_F);

    unsigned mall, mopp;
    if (structured && mypid == pp2 && window_clear) {
        mall = 2u; mopp = 1u;    // canonical: matches are exactly {p, P_+p}
    } else {
        const int jb = (gr < N_ / 2) ? P_ : 0;
        mall = 0u; mopp = 0u;
        for (int j = 0; j < TWOP; ++j) {
            if (gp[j] == mypid) {
                ++mall;
                if (j >= jb && j < jb + P_) {
                    ++mopp;
                    if (j != pg) {
                        unsigned s0 = atomicAdd(&counters[0], 1u);
                        if (s0 < EXCAP) extralist[s0] = gr * TWOP + j;
                        else atomicExch(&counters[2], 1u);
                    }
                }
            } else if (fabsf(myxn - shn[j]) < MARGIN_F) {
                unsigned s0 = atomicAdd(&counters[1], 1u);
                if (s0 < FLAGCAP) flaglist[s0] = gr * TWOP + j;
                else atomicExch(&counters[2], 1u);
            }
        }
    }

    float s1 = (gp[pg] == mypid) ? dist : 0.f;
    unsigned neg = (unsigned)TWOP - mall;
    unsigned mo = mopp;
    #pragma unroll
    for (int o = 32; o > 0; o >>= 1) {
        s1  += __shfl_xor(s1, o, 64);
        mo  += __shfl_xor(mo, o, 64);
        neg += __shfl_xor(neg, o, 64);
    }
    if (lane == 0) { rf[wv] = s1; ru[wv] = mo; rn[wv] = neg; }
    __syncthreads();
    if (t == 0) {
        atomicExch(&s1part[blockIdx.x],  rf[0] + rf[1] + rf[2] + rf[3]);
        atomicExch(&c1part[blockIdx.x],  ru[0] + ru[1] + ru[2] + ru[3]);
        atomicExch(&negpart[blockIdx.x], rn[0] + rn[1] + rn[2] + rn[3]);
    }

    // ---- arrival: last block performs final phase
    __threadfence();
    if (t == 0) {
        const unsigned n = atomicAdd(&counters[3], 1u);
        sLast = (n == NTAILB - 1) ? 1 : 0;
    }
    __syncthreads();
    if (!sLast) return;
    __threadfence();   // acquire: see all blocks' partials/lists

    {
        float s1v = 0.f; unsigned c1v = 0u, ngv = 0u;
        if (t < NTAILB) { s1v = s1part[t]; c1v = c1part[t]; ngv = negpart[t]; }
        if (t < 64) {
            #pragma unroll
            for (int o = 32; o > 0; o >>= 1) {
                s1v += __shfl_xor(s1v, o, 64);
                c1v += __shfl_xor(c1v, o, 64);
                ngv += __shfl_xor(ngv, o, 64);
            }
            if (t == 0) { bc_s1 = s1v; bc_c1 = (float)c1v; bc_ng = (float)ngv; }
        }
    }
    __syncthreads();

    // exact fallback for extras (loss1) and flagged pairs (hinge); expected 0
    unsigned ne = counters[0]; if (ne > EXCAP)   ne = EXCAP;
    unsigned nf = counters[1]; if (nf > FLAGCAP) nf = FLAGCAP;
    float s1x = 0.f, l2 = 0.f;
    const float4* x4 = (const float4*)x;
    for (unsigned u = 0; u < ne + nf; ++u) {
        const bool isex = (u < ne);
        const int code = isex ? extralist[u] : flaglist[u - ne];
        const int i = code >> 9, jj = code & (TWOP - 1);
        const float4* xr = x4 + (size_t)i * C4_;
        const float4* gb = x4 + (size_t)jj * K_ * C4_;
        float dp = 0.f, sqi = 0.f;
        for (int c = t; c < C4_; c += 256) {
            const float4 a = xr[c];
            float hx = 0.f, hy = 0.f, hz = 0.f, hw = 0.f;
            #pragma unroll
            for (int rr = 0; rr < K_; ++rr) {
                const float4 u4 = gb[(size_t)rr * C4_ + c];
                hx += u4.x; hy += u4.y; hz += u4.z; hw += u4.w;
            }
            dp  += (a.x*hx + a.y*hy + a.z*hz + a.w*hw) * 0.0625f;
            sqi += a.x*a.x + a.y*a.y + a.z*a.z + a.w*a.w;
        }
        #pragma unroll
        for (int o = 32; o > 0; o >>= 1) {
            dp  += __shfl_xor(dp, o, 64);
            sqi += __shfl_xor(sqi, o, 64);
        }
        if (lane == 0) { rf[wv] = dp; smin[wv] = sqi; }
        __syncthreads();
        if (t == 0) {
            const float ddot = rf[0] + rf[1] + rf[2] + rf[3];
            const float sqv  = smin[0] + smin[1] + smin[2] + smin[3];
            const float d2 = sqv + sh2[jj] - 2.0f * ddot;
            const float dist2 = sqrtf(fmaxf(d2, 1e-12f));
            if (isex) s1x += dist2;
            else { const float h = MARGIN_F - dist2; if (h > 0.f) l2 += h; }
        }
        __syncthreads();
    }

    if (t == 0) out[0] = (bc_s1 + s1x) / bc_c1 + l2 / bc_ng;
}

// ---------------------------------------------------------------------------
extern "C" void kernel_launch(void* const* d_in, const int* in_sizes, int n_in,
                              void* d_out, int out_size, void* d_ws, size_t ws_size,
                              hipStream_t stream) {
    const float* x    = (const float*)d_in[0];
    const int*   pids = (const int*)d_in[1];

    float* ws = (float*)d_ws;
    float*    dot_part = ws;                                    // 256*8*32 = 65536
    float*    sq_part  = dot_part + P_ * NSL * 32;              // 65536
    float*    hn2_part = sq_part + P_ * NSL * 32;               // 256*8*4 = 8192
    float*    s1part   = hn2_part + P_ * NSL * 4;               // 32
    unsigned* c1part   = (unsigned*)(s1part + NTAILB);          // 32
    unsigned* negpart  = c1part + NTAILB;                       // 32
    unsigned* counters = negpart + NTAILB;                      // 4
    int*      extralist= (int*)(counters + 4);                  // EXCAP
    int*      flaglist = extralist + EXCAP;                     // FLAGCAP

    hipLaunchKernelGGL(k_fused, dim3(P_ * NSL), dim3(256), 0, stream,
                       x, dot_part, sq_part, hn2_part, counters);
    hipLaunchKernelGGL(k_tail,  dim3(NTAILB),   dim3(256), 0, stream,
                       x, dot_part, sq_part, hn2_part, pids,
                       s1part, c1part, negpart, counters,
                       extralist, flaglist, (float*)d_out);
}